// Round 2
// baseline (238.289 us; speedup 1.0000x reference)
//
#include <hip/hip_runtime.h>
#include <hip/hip_bf16.h>

typedef __hip_bfloat16 bf16;

__device__ __forceinline__ float b2f(bf16 v) { return __bfloat162float(v); }

constexpr int B = 2, S = 2048, E = 1024, H = 16, D = 64;

// Uniform-branch load/store: isf32 is the same for every lane (read from ws flag).
__device__ __forceinline__ float ldin(const void* p, size_t i, int isf32) {
  return isf32 ? ((const float*)p)[i] : b2f(((const bf16*)p)[i]);
}
__device__ __forceinline__ void stout(void* p, size_t i, int isf32, float v) {
  if (isf32) ((float*)p)[i] = v;
  else       ((bf16*)p)[i] = __float2bfloat16(v);
}

// ---------------------------------------------------------------------------
// K0: dtype detector. Scan first 4096 32-bit words of Wq. If data is fp32
// (|w|~0.02), the low 16 bits are random mantissa bits -> as-bf16 exponent
// >= 127 with ~50% prob/word. If data is bf16, every 16-bit half is a weight
// with exponent <= ~0x7B. flag=1 => fp32.
__global__ void k_detect(const unsigned int* __restrict__ wq, int* __restrict__ flag) {
  __shared__ int bad;
  if (threadIdx.x == 0) bad = 0;
  __syncthreads();
  int mybad = 0;
  for (int i = threadIdx.x; i < 4096; i += 256) {
    unsigned lo = wq[i] & 0xFFFFu;
    unsigned e = (lo >> 7) & 0xFF;
    if (e >= 127) mybad = 1;
  }
  if (mybad) atomicOr(&bad, 1);
  __syncthreads();
  if (threadIdx.x == 0) *flag = bad;
}

// ---------------------------------------------------------------------------
// K1: q_vec[b*E + n] = sum_e inputs[b, S-1, e] * Wq[n, e]
__global__ void k_qvec(const void* __restrict__ inputs, const void* __restrict__ Wq,
                       float* __restrict__ q_vec, const int* __restrict__ flag) {
  int isf32 = *flag;
  int wave = (blockIdx.x * blockDim.x + threadIdx.x) >> 6;
  int lane = threadIdx.x & 63;
  if (wave >= B * E) return;
  int b = wave / E, n = wave % E;
  size_t xoff = (size_t)b * S * E + (size_t)(S - 1) * E;
  size_t woff = (size_t)n * E;
  float acc = 0.f;
  for (int e = lane; e < E; e += 64)
    acc += ldin(inputs, xoff + e, isf32) * ldin(Wq, woff + e, isf32);
  for (int off = 32; off > 0; off >>= 1) acc += __shfl_down(acc, off, 64);
  if (lane == 0) q_vec[wave] = acc;
}

// ---------------------------------------------------------------------------
// K2: wkq[b,h,e] = sum_d q_vec[b, h*D+d] * Wk[h*D+d, e]
__global__ void k_wkq(const float* __restrict__ q_vec, const void* __restrict__ Wk,
                      float* __restrict__ wkq, const int* __restrict__ flag) {
  int isf32 = *flag;
  int b = blockIdx.x / H, h = blockIdx.x % H;
  __shared__ float qh[D];
  int tid = threadIdx.x;
  if (tid < D) qh[tid] = q_vec[b * E + h * D + tid];
  __syncthreads();
  for (int e = tid; e < E; e += blockDim.x) {
    float acc = 0.f;
    #pragma unroll 8
    for (int d = 0; d < D; ++d)
      acc += qh[d] * ldin(Wk, (size_t)(h * D + d) * E + e, isf32);
    wkq[((size_t)b * H + h) * E + e] = acc;
  }
}

// ---------------------------------------------------------------------------
// K3: scores[b,h,k] = sum_e embK[b,k,e] * wkq[b,h,e]
__global__ void k_scores(const void* __restrict__ embK, const float* __restrict__ wkq,
                         float* __restrict__ scores, const int* __restrict__ flag) {
  int isf32 = *flag;
  int b = blockIdx.x / S, k = blockIdx.x % S;
  __shared__ float row[E];
  int tid = threadIdx.x;
  for (int e = tid; e < E; e += blockDim.x)
    row[e] = ldin(embK, ((size_t)b * S + k) * E + e, isf32);
  __syncthreads();
  int wave = tid >> 6, lane = tid & 63;
  for (int h = wave; h < H; h += (blockDim.x >> 6)) {
    const float* w = wkq + ((size_t)b * H + h) * E;
    float acc = 0.f;
    for (int e = lane; e < E; e += 64) acc += row[e] * w[e];
    for (int off = 32; off > 0; off >>= 1) acc += __shfl_down(acc, off, 64);
    if (lane == 0) scores[((size_t)b * H + h) * S + k] = acc;
  }
}

// ---------------------------------------------------------------------------
// K4: softmax in-place over scores[row, :]   (UNSCALED, per ref)
__global__ void k_softmax(float* __restrict__ scores) {
  int row = blockIdx.x;
  float* s = scores + (size_t)row * S;
  __shared__ float red[256];
  int tid = threadIdx.x;
  float m = -1e30f;
  for (int i = tid; i < S; i += 256) m = fmaxf(m, s[i]);
  red[tid] = m; __syncthreads();
  for (int o = 128; o > 0; o >>= 1) { if (tid < o) red[tid] = fmaxf(red[tid], red[tid + o]); __syncthreads(); }
  m = red[0]; __syncthreads();
  float sum = 0.f;
  for (int i = tid; i < S; i += 256) sum += expf(s[i] - m);
  red[tid] = sum; __syncthreads();
  for (int o = 128; o > 0; o >>= 1) { if (tid < o) red[tid] += red[tid + o]; __syncthreads(); }
  float inv = 1.f / red[0];
  for (int i = tid; i < S; i += 256) s[i] = expf(s[i] - m) * inv;
}

// ---------------------------------------------------------------------------
__global__ void k_zero(float* __restrict__ p, int n) {
  int i = blockIdx.x * blockDim.x + threadIdx.x;
  if (i < n) p[i] = 0.f;
}

// K5: ctx[b,h,e] += sum_{k in chunk} p[b,h,k] * embV[b,k,e]
constexpr int KC = 128;
__global__ void k_ctx(const void* __restrict__ embV, const float* __restrict__ p,
                      float* __restrict__ ctx, const int* __restrict__ flag) {
  int isf32 = *flag;
  int b = blockIdx.x, ec = blockIdx.y, kc = blockIdx.z;
  int tid = threadIdx.x;
  int e = ec * 256 + tid;
  int k0 = kc * KC;
  __shared__ float pl[H * KC];
  for (int i = tid; i < H * KC; i += 256) {
    int h = i / KC, kk = i % KC;
    pl[i] = p[((size_t)b * H + h) * S + k0 + kk];
  }
  __syncthreads();
  float acc[H];
  #pragma unroll
  for (int h = 0; h < H; ++h) acc[h] = 0.f;
  for (int kk = 0; kk < KC; ++kk) {
    float v = ldin(embV, ((size_t)b * S + k0 + kk) * E + e, isf32);
    #pragma unroll
    for (int h = 0; h < H; ++h) acc[h] += pl[h * KC + kk] * v;
  }
  #pragma unroll
  for (int h = 0; h < H; ++h)
    atomicAdd(&ctx[((size_t)b * H + h) * E + e], acc[h]);
}

// ---------------------------------------------------------------------------
// K6: o_vec[b*E + n] = sum_e ctx[b, n/D, e] * Wv[n, e]
__global__ void k_ovec(const float* __restrict__ ctx, const void* __restrict__ Wv,
                       float* __restrict__ o_vec, const int* __restrict__ flag) {
  int isf32 = *flag;
  int wave = (blockIdx.x * blockDim.x + threadIdx.x) >> 6;
  int lane = threadIdx.x & 63;
  if (wave >= B * E) return;
  int b = wave / E, n = wave % E;
  const float* x = ctx + ((size_t)b * H + n / D) * E;
  size_t woff = (size_t)n * E;
  float acc = 0.f;
  for (int e = lane; e < E; e += 64) acc += x[e] * ldin(Wv, woff + e, isf32);
  for (int off = 32; off > 0; off >>= 1) acc += __shfl_down(acc, off, 64);
  if (lane == 0) o_vec[wave] = acc;
}

// K7: out_vec[b*E + n] = sum_e o_vec[b*E + e] * Wo[n, e]
__global__ void k_outvec(const float* __restrict__ o_vec, const void* __restrict__ Wo,
                         float* __restrict__ out_vec, const int* __restrict__ flag) {
  int isf32 = *flag;
  int wave = (blockIdx.x * blockDim.x + threadIdx.x) >> 6;
  int lane = threadIdx.x & 63;
  if (wave >= B * E) return;
  int b = wave / E, n = wave % E;
  const float* x = o_vec + (size_t)b * E;
  size_t woff = (size_t)n * E;
  float acc = 0.f;
  for (int e = lane; e < E; e += 64) acc += x[e] * ldin(Wo, woff + e, isf32);
  for (int off = 32; off > 0; off >>= 1) acc += __shfl_down(acc, off, 64);
  if (lane == 0) out_vec[wave] = acc;
}

// ---------------------------------------------------------------------------
// K8: broadcast out_vec[b,:] over all S rows; store in detected output dtype
__global__ void k_bcast(const float* __restrict__ out_vec, void* __restrict__ out,
                        const int* __restrict__ flag) {
  int isf32 = *flag;
  size_t idx = (size_t)blockIdx.x * blockDim.x + threadIdx.x;
  if (idx >= (size_t)B * S * E) return;
  int e = (int)(idx % E);
  int b = (int)(idx / ((size_t)S * E));
  stout(out, idx, isf32, out_vec[b * E + e]);
}

// ---------------------------------------------------------------------------
extern "C" void kernel_launch(void* const* d_in, const int* in_sizes, int n_in,
                              void* d_out, int out_size, void* d_ws, size_t ws_size,
                              hipStream_t stream) {
  const void* inputs = d_in[0];
  const void* embV   = d_in[1];
  const void* embK   = d_in[2];
  const void* Wq     = d_in[3];
  const void* Wk     = d_in[4];
  const void* Wv     = d_in[5];
  const void* Wo     = d_in[6];

  float* ws      = (float*)d_ws;
  float* q_vec   = ws;                    // B*E      = 2048
  float* wkq     = q_vec + B * E;         // B*H*E    = 32768
  float* scores  = wkq + B * H * E;       // B*H*S    = 65536
  float* ctx     = scores + B * H * S;    // B*H*E    = 32768
  float* o_vec   = ctx + B * H * E;       // B*E      = 2048
  float* out_vec = o_vec + B * E;         // B*E      = 2048
  int*   flag    = (int*)(out_vec + B * E);

  k_detect<<<1, 256, 0, stream>>>((const unsigned int*)Wq, flag);
  k_zero<<<(B * H * E + 255) / 256, 256, 0, stream>>>(ctx, B * H * E);
  k_qvec<<<B * E / 4, 256, 0, stream>>>(inputs, Wq, q_vec, flag);
  k_wkq<<<B * H, 256, 0, stream>>>(q_vec, Wk, wkq, flag);
  k_scores<<<B * S, 256, 0, stream>>>(embK, wkq, scores, flag);
  k_softmax<<<B * H, 256, 0, stream>>>(scores);
  k_ctx<<<dim3(B, E / 256, S / KC), 256, 0, stream>>>(embV, scores, ctx, flag);
  k_ovec<<<B * E / 4, 256, 0, stream>>>(ctx, Wv, o_vec, flag);
  k_outvec<<<B * E / 4, 256, 0, stream>>>(o_vec, Wo, out_vec, flag);
  k_bcast<<<(B * S * E + 255) / 256, 256, 0, stream>>>(out_vec, d_out, flag);
}

// Round 3
// 156.992 us; speedup vs baseline: 1.5178x; 1.5178x over previous
//
#include <hip/hip_runtime.h>
#include <hip/hip_bf16.h>

// All inputs/outputs are fp32 (proven: round-1 bf16 reinterpretation -> NaN;
// round-2 passed storing fp32).

constexpr int B = 2, S = 2048, E = 1024, H = 16, D = 64;
constexpr int E4 = E / 4;  // 256 float4 per row

// ---------------------------------------------------------------------------
// K1: q_vec[b*E + n] = sum_e x[b,S-1,e] * Wq[n,e]
// grid 256 blocks x 256 thr; block = (b, 8 consecutive n); 32-lane e-split.
__global__ void k_qvec(const float4* __restrict__ x, const float4* __restrict__ Wq,
                       float* __restrict__ q_vec) {
  int blk = blockIdx.x;
  int b = blk >> 7, n0 = (blk & 127) * 8;
  int tid = threadIdx.x;
  int nl = tid >> 5, es = tid & 31;
  const float4* xr = x + ((size_t)b * S + (S - 1)) * E4;
  const float4* wr = Wq + (size_t)(n0 + nl) * E4;
  float acc = 0.f;
#pragma unroll
  for (int j = 0; j < 8; ++j) {
    float4 a = xr[es + 32 * j];
    float4 w = wr[es + 32 * j];
    acc += a.x * w.x + a.y * w.y + a.z * w.z + a.w * w.w;
  }
#pragma unroll
  for (int o = 16; o > 0; o >>= 1) acc += __shfl_xor(acc, o, 64);
  if (es == 0) q_vec[b * E + n0 + nl] = acc;
}

// ---------------------------------------------------------------------------
// K2: wkq[b,h,e] = sum_d q_vec[b,h*D+d] * Wk[h*D+d,e]; also zeroes ctx.
// grid 256 = (b,h,eo) x 128 thr; thread per e in 128-slice.
__global__ void k_wkq(const float* __restrict__ q_vec, const float* __restrict__ Wk,
                      float* __restrict__ wkq, float* __restrict__ ctx) {
  int blk = blockIdx.x;
  int eo = blk & 7;
  int bh = blk >> 3;            // b*H + h
  int h = bh & 15;
  int tid = threadIdx.x;
  __shared__ float qh[D];
  if (tid < D) qh[tid] = q_vec[(bh >> 4) * E + h * D + tid];
  __syncthreads();
  int e = eo * 128 + tid;
  const float* wp = Wk + (size_t)h * D * E + e;
  float acc = 0.f;
#pragma unroll 8
  for (int d = 0; d < D; ++d) acc += qh[d] * wp[(size_t)d * E];
  wkq[(size_t)bh * E + e] = acc;
  ctx[(size_t)bh * E + e] = 0.f;   // pre-zero for k_ctx atomics
}

// ---------------------------------------------------------------------------
// K3: scores[b,h,k] = embK[b,k,:] . wkq[b,h,:]
// grid 256 blocks (1/CU) x 256 thr. wkq[b] (64KB) in LDS; thread = (k of 16,
// es of 16): holds 64-float embK slice in regs, streams wkq via ds_read_b128.
__global__ __launch_bounds__(256) void k_scores(const float4* __restrict__ embK,
                                                const float4* __restrict__ wkq4,
                                                float* __restrict__ scores) {
  __shared__ float4 wl[H * E4];  // 64 KB
  int blk = blockIdx.x;
  int b = blk >> 7, k0 = (blk & 127) * 16;
  int tid = threadIdx.x;
#pragma unroll
  for (int j = 0; j < 16; ++j)
    wl[j * 256 + tid] = wkq4[(size_t)b * (H * E4) + j * 256 + tid];
  __syncthreads();
  int k = tid >> 4, es = tid & 15;
  const float4* er = embK + ((size_t)b * S + k0 + k) * E4;
  float4 v[16];
#pragma unroll
  for (int j = 0; j < 16; ++j) v[j] = er[es + 16 * j];
#pragma unroll 1
  for (int h = 0; h < H; ++h) {
    float acc = 0.f;
#pragma unroll
    for (int j = 0; j < 16; ++j) {
      float4 w = wl[h * 256 + es + 16 * j];
      acc += v[j].x * w.x + v[j].y * w.y + v[j].z * w.z + v[j].w * w.w;
    }
#pragma unroll
    for (int o = 8; o > 0; o >>= 1) acc += __shfl_xor(acc, o, 64);
    if (es == 0) scores[((size_t)(b * H + h)) * S + k0 + k] = acc;
  }
}

// ---------------------------------------------------------------------------
// K4: softmax in-place over scores[row,:] (UNSCALED per ref). 32 blocks.
__global__ void k_softmax(float* __restrict__ scores) {
  int row = blockIdx.x;
  float* s = scores + (size_t)row * S;
  __shared__ float red[256];
  int tid = threadIdx.x;
  float m = -1e30f;
  for (int i = tid; i < S; i += 256) m = fmaxf(m, s[i]);
  red[tid] = m; __syncthreads();
  for (int o = 128; o > 0; o >>= 1) { if (tid < o) red[tid] = fmaxf(red[tid], red[tid + o]); __syncthreads(); }
  m = red[0]; __syncthreads();
  float sum = 0.f;
  for (int i = tid; i < S; i += 256) { float t = __expf(s[i] - m); s[i] = t; sum += t; }
  red[tid] = sum; __syncthreads();
  for (int o = 128; o > 0; o >>= 1) { if (tid < o) red[tid] += red[tid + o]; __syncthreads(); }
  float inv = 1.f / red[0];
  for (int i = tid; i < S; i += 256) s[i] *= inv;
}

// ---------------------------------------------------------------------------
// K5: ctx[b,h,e] += sum_k p[b,h,k] * embV[b,k,e]
// grid (B,2,32) x 256 thr: e-half x k-chunk-of-64; thread pair (ksub) splits
// the chunk; shfl-combine then fp32 atomics (32-way inter-block contention).
__global__ __launch_bounds__(256) void k_ctx(const float4* __restrict__ embV,
                                             const float* __restrict__ p,
                                             float* __restrict__ ctx) {
  int b = blockIdx.x, eo = blockIdx.y, kz = blockIdx.z;
  int tid = threadIdx.x;
  int e4l = tid >> 1, ksub = tid & 1;
  int k0 = kz * 64;
  __shared__ float pl[H * 64];  // 4 KB
  for (int i = tid; i < H * 64; i += 256) {
    int h = i >> 6, kk = i & 63;
    pl[i] = p[((size_t)(b * H + h)) * S + k0 + kk];
  }
  __syncthreads();
  int e4 = eo * 128 + e4l;
  float4 acc[H];
#pragma unroll
  for (int h = 0; h < H; ++h) acc[h] = make_float4(0.f, 0.f, 0.f, 0.f);
  int kbase = ksub * 32;
  for (int i = 0; i < 32; ++i) {
    int kk = kbase + i;
    float4 v = embV[((size_t)b * S + k0 + kk) * E4 + e4];
#pragma unroll
    for (int h = 0; h < H; ++h) {
      float pv = pl[h * 64 + kk];   // wave-uniform-ish broadcast (2 addrs, free)
      acc[h].x += pv * v.x; acc[h].y += pv * v.y;
      acc[h].z += pv * v.z; acc[h].w += pv * v.w;
    }
  }
#pragma unroll
  for (int h = 0; h < H; ++h) {
    acc[h].x += __shfl_xor(acc[h].x, 1, 64);
    acc[h].y += __shfl_xor(acc[h].y, 1, 64);
    acc[h].z += __shfl_xor(acc[h].z, 1, 64);
    acc[h].w += __shfl_xor(acc[h].w, 1, 64);
  }
  if (ksub == 0) {
#pragma unroll
    for (int h = 0; h < H; ++h) {
      float* c = ctx + ((size_t)(b * H + h)) * E + e4 * 4;
      atomicAdd(c + 0, acc[h].x);
      atomicAdd(c + 1, acc[h].y);
      atomicAdd(c + 2, acc[h].z);
      atomicAdd(c + 3, acc[h].w);
    }
  }
}

// ---------------------------------------------------------------------------
// K6: o_vec[b*E+n] = ctx[b, n/64, :] . Wv[n, :]   (wave per n, float4)
__global__ void k_ovec(const float* __restrict__ ctx, const float4* __restrict__ Wv4,
                       float* __restrict__ o_vec) {
  int gw = (blockIdx.x * blockDim.x + threadIdx.x) >> 6;
  int lane = threadIdx.x & 63;
  int b = gw >> 10, nn = gw & 1023;
  const float4* xr = (const float4*)(ctx + ((size_t)(b * H + (nn >> 6))) * E);
  const float4* wr = Wv4 + (size_t)nn * E4;
  float acc = 0.f;
#pragma unroll
  for (int j = 0; j < 4; ++j) {
    float4 a = xr[lane + 64 * j];
    float4 w = wr[lane + 64 * j];
    acc += a.x * w.x + a.y * w.y + a.z * w.z + a.w * w.w;
  }
#pragma unroll
  for (int o = 32; o > 0; o >>= 1) acc += __shfl_xor(acc, o, 64);
  if (lane == 0) o_vec[gw] = acc;
}

// K7: out_vec[b*E+n] = o_vec[b,:] . Wo[n,:]   (wave per n, float4)
__global__ void k_outvec(const float* __restrict__ o_vec, const float4* __restrict__ Wo4,
                         float* __restrict__ out_vec) {
  int gw = (blockIdx.x * blockDim.x + threadIdx.x) >> 6;
  int lane = threadIdx.x & 63;
  int b = gw >> 10, nn = gw & 1023;
  const float4* xr = (const float4*)(o_vec + (size_t)b * E);
  const float4* wr = Wo4 + (size_t)nn * E4;
  float acc = 0.f;
#pragma unroll
  for (int j = 0; j < 4; ++j) {
    float4 a = xr[lane + 64 * j];
    float4 w = wr[lane + 64 * j];
    acc += a.x * w.x + a.y * w.y + a.z * w.z + a.w * w.w;
  }
#pragma unroll
  for (int o = 32; o > 0; o >>= 1) acc += __shfl_xor(acc, o, 64);
  if (lane == 0) out_vec[gw] = acc;
}

// ---------------------------------------------------------------------------
// K8: out[b,s,:] = out_vec[b,:] for all s, float4 stores.
// total float4 = B*S*E4 = 2^20; 1024 blocks x 256 thr x 4 each.
__global__ void k_bcast(const float4* __restrict__ ov4, float4* __restrict__ out4) {
  int base = blockIdx.x * 1024 + threadIdx.x;
#pragma unroll
  for (int r = 0; r < 4; ++r) {
    int g = base + r * 256;
    out4[g] = ov4[(g >> 19) * E4 + (g & 255)];  // b = g / (S*E4), e4 = g & 255
  }
}

// ---------------------------------------------------------------------------
extern "C" void kernel_launch(void* const* d_in, const int* in_sizes, int n_in,
                              void* d_out, int out_size, void* d_ws, size_t ws_size,
                              hipStream_t stream) {
  const float* inputs = (const float*)d_in[0];
  const float* embV   = (const float*)d_in[1];
  const float* embK   = (const float*)d_in[2];
  const float* Wq     = (const float*)d_in[3];
  const float* Wk     = (const float*)d_in[4];
  const float* Wv     = (const float*)d_in[5];
  const float* Wo     = (const float*)d_in[6];

  float* ws      = (float*)d_ws;
  float* q_vec   = ws;                   // 2048
  float* wkq     = q_vec + B * E;        // 32768
  float* scores  = wkq + B * H * E;      // 65536
  float* ctx     = scores + B * H * S;   // 32768
  float* o_vec   = ctx + B * H * E;      // 2048
  float* out_vec = o_vec + B * E;        // 2048

  k_qvec<<<256, 256, 0, stream>>>((const float4*)inputs, (const float4*)Wq, q_vec);
  k_wkq<<<256, 128, 0, stream>>>(q_vec, Wk, wkq, ctx);
  k_scores<<<256, 256, 0, stream>>>((const float4*)embK, (const float4*)wkq, scores);
  k_softmax<<<32, 256, 0, stream>>>(scores);
  k_ctx<<<dim3(B, 2, 32), 256, 0, stream>>>((const float4*)embV, scores, ctx);
  k_ovec<<<512, 256, 0, stream>>>(ctx, (const float4*)Wv, o_vec);
  k_outvec<<<512, 256, 0, stream>>>(o_vec, (const float4*)Wo, out_vec);
  k_bcast<<<1024, 256, 0, stream>>>((const float4*)out_vec, (float4*)d_out);
}